// Round 1
// baseline (8528.877 us; speedup 1.0000x reference)
//
#include <hip/hip_runtime.h>
#include <hip/hip_bf16.h>

#define T_STEPS 800
#define BATCH   32
#define FEAT    161
#define UNITS   1024
#define CLIPV   20.0f

typedef __attribute__((ext_vector_type(8))) short short8;
typedef __attribute__((ext_vector_type(4))) float f32x4;
typedef unsigned short u16;
typedef unsigned int   u32;
typedef unsigned long long u64;

__device__ __forceinline__ float bf16_f(u16 u) {
    return __uint_as_float(((u32)u) << 16);
}
__device__ __forceinline__ u16 bf16_rn(float x) {
    __hip_bfloat16 b = __float2bfloat16(x);
    return *(u16*)&b;
}
__device__ __forceinline__ u64 ld_agent_u64(const u64* p) {
    return __hip_atomic_load(p, __ATOMIC_RELAXED, __HIP_MEMORY_SCOPE_AGENT);
}
__device__ __forceinline__ void st_agent_u64(u64* p, u64 v) {
    __hip_atomic_store(p, v, __ATOMIC_RELAXED, __HIP_MEMORY_SCOPE_AGENT);
}
__device__ __forceinline__ short8 ld_agent_b16x8(const u16* p) {
    union { u64 q[2]; short8 v; } u;
    u.q[0] = ld_agent_u64((const u64*)p);
    u.q[1] = ld_agent_u64((const u64*)p + 1);
    return u.v;
}

// ---------------------------------------------------------------------------
// zero h double-buffer (2 x 64 x 1024 packed u64). tag16 field = 0 == state 0,
// so step-0 consumers accept the zero init directly; buffer 1's zeros (tag 0)
// can never satisfy any consumer target >= 1.
__global__ __launch_bounds__(256) void init_ws(u64* hbuf) {
    int gid = blockIdx.x * 256 + threadIdx.x;         // 16384 threads
    for (int i = gid; i < 2 * 64 * UNITS; i += 64 * 256) hbuf[i] = 0ull;
}

// ---------------------------------------------------------------------------
// Ut splits: U[k][u] fp32 -> Ut1/2/3[u][k] bf16 (hi/mid/lo, 24-bit total)
__global__ __launch_bounds__(256) void u_split_t(const float* __restrict__ U,
                                                 u16* __restrict__ Ut1,
                                                 u16* __restrict__ Ut2,
                                                 u16* __restrict__ Ut3) {
    __shared__ float tile[32][33];
    int bx = blockIdx.x, by = blockIdx.y;
    int lx = threadIdx.x & 31;
    int ly4 = (threadIdx.x >> 5) * 4;
    #pragma unroll
    for (int j = 0; j < 4; ++j)
        tile[ly4 + j][lx] = U[(size_t)(by * 32 + ly4 + j) * UNITS + bx * 32 + lx];
    __syncthreads();
    #pragma unroll
    for (int j = 0; j < 4; ++j) {
        float x = tile[lx][ly4 + j];
        size_t o = (size_t)(bx * 32 + ly4 + j) * UNITS + by * 32 + lx;
        u16 s1 = bf16_rn(x);  float r1 = x - bf16_f(s1);
        u16 s2 = bf16_rn(r1); float r2 = r1 - bf16_f(s2);
        u16 s3 = bf16_rn(r2);
        Ut1[o] = s1; Ut2[o] = s2; Ut3[o] = s3;
    }
}

// ---------------------------------------------------------------------------
__global__ __launch_bounds__(256) void xw_gemm(const float* __restrict__ inp,
                                               const float* __restrict__ W,
                                               const float* __restrict__ bias,
                                               float* __restrict__ xW) {
    __shared__ float xs[8 * FEAT];
    int t = blockIdx.x;
    int b0 = blockIdx.y * 8;
    int tid = threadIdx.x;

    for (int i = tid; i < 8 * FEAT; i += 256) {
        int j = i / FEAT;
        int f = i - j * FEAT;
        xs[i] = inp[((size_t)(b0 + j) * T_STEPS + t) * FEAT + f];
    }
    __syncthreads();

    float bv[4];
    #pragma unroll
    for (int c = 0; c < 4; ++c) bv[c] = bias[tid + c * 256];

    float acc[8][4];
    #pragma unroll
    for (int j = 0; j < 8; ++j)
        #pragma unroll
        for (int c = 0; c < 4; ++c) acc[j][c] = bv[c];

    for (int f = 0; f < FEAT; ++f) {
        float w0 = W[(size_t)f * UNITS + tid];
        float w1 = W[(size_t)f * UNITS + tid + 256];
        float w2 = W[(size_t)f * UNITS + tid + 512];
        float w3 = W[(size_t)f * UNITS + tid + 768];
        #pragma unroll
        for (int j = 0; j < 8; ++j) {
            float xv = xs[j * FEAT + f];
            acc[j][0] += xv * w0;
            acc[j][1] += xv * w1;
            acc[j][2] += xv * w2;
            acc[j][3] += xv * w3;
        }
    }

    #pragma unroll
    for (int j = 0; j < 8; ++j)
        #pragma unroll
        for (int c = 0; c < 4; ++c)
            xW[((size_t)t * BATCH + b0 + j) * UNITS + tid + c * 256] = acc[j][c];
}

// ---------------------------------------------------------------------------
// Dataflow MFMA scan. 128 blocks x 512 threads.
// Block (rg 0..3, ug 0..31): rows [rg*16,+16) (row = dir*32+b), cols [ug*32,+32).
// Wave kq: k-slice [kq*128,+128).
//
// Sync = FULL 16-bit step tag embedded in each packed h word:
//   u64 = s1 | s2<<16 | s3<<32 | tag<<48   (s1..s3 = exact bf16x3 trunc split)
// A consumer at step t polls its own data words until tag == t; a matching tag
// IS the value (8B store is atomic), so there is no flag array, no producer
// vmcnt drain, and no second post-flag load. Full tags (not parity) make this
// immune to relaxed-store visibility reordering.
// WAR with 2 buffers: writer of state s+2 first observed ALL of state s+1 for
// its rows, which each producer published only after its barrier (vmcnt(0)
// drained => its waves' state-s loads complete). So no reader of state s can
// still be mid-load when s+2 overwrites it. Same chain bounds skew so a stale
// tag can never alias (tags are exact, anyway).
__global__ __launch_bounds__(512) void rnn_scan(
        const float* __restrict__ xW,
        const u16* __restrict__ Ut1, const u16* __restrict__ Ut2,
        const u16* __restrict__ Ut3,
        u64* __restrict__ hbuf,
        float* __restrict__ out) {
    __shared__ f32x4 red[2][8][2][64];   // 32 KB, double-buffered -> 1 barrier/step

    const int tid  = threadIdx.x;
    const int bk   = blockIdx.x;
    const int lane = tid & 63;
    const int kq   = tid >> 6;       // 0..7
    const int quad = lane >> 4;      // 0..3
    const int n16  = lane & 15;
    const int rg   = bk & 3;
    const int ug   = bk >> 2;
    const int R0   = rg * 16;
    const int u0   = ug * 32;
    const int dir  = rg >> 1;

    // output-element ownership for the all-wave reduce/store tail (1 elem/lane)
    const int er  = tid >> 5;                      // 0..15 row in group
    const int ec  = tid & 31;                      // 0..31 col in group
    const int enq = ec >> 4;
    const int ele = ((er >> 2) << 4) + (ec & 15);  // source lane in red[]
    const int eje = er & 3;                        // f32x4 element
    const int eb  = (R0 + er) & 31;                // batch row for xW
    const size_t hoff = (size_t)(R0 + er) * UNITS + (u0 + ec);

    // --- B fragments (atomic loads -> not rematerializable -> stay in regs) ---
    short8 bfr[4][2][3];
    #pragma unroll
    for (int ks = 0; ks < 4; ++ks) {
        const int koff = kq * 128 + ks * 32 + quad * 8;
        #pragma unroll
        for (int nq = 0; nq < 2; ++nq) {
            const size_t ub = (size_t)(u0 + nq * 16 + n16) * UNITS + koff;
            bfr[ks][nq][0] = ld_agent_b16x8(Ut1 + ub);
            bfr[ks][nq][1] = ld_agent_b16x8(Ut2 + ub);
            bfr[ks][nq][2] = ld_agent_b16x8(Ut3 + ub);
        }
    }

    const size_t HS = (size_t)64 * UNITS;            // u64 elems per buffer

    for (int t = 0; t < T_STEPS; ++t) {
        const size_t sb = (size_t)(t & 1) * HS;
        const size_t db = sb ^ HS;
        const int tb = t & 1;

        // per-lane xW prefetch (own output element; latency hides under poll)
        const int xt = dir ? (T_STEPS - 1 - t) : t;
        const float xv = xW[(size_t)xt * (BATCH * UNITS) +
                            (size_t)eb * UNITS + (u0 + ec)];

        // ---- poll own data words (tag==t) and build A fragments in place ----
        const u64* abase = hbuf + sb + (size_t)(R0 + n16) * UNITS + kq * 128;
        short8 fa1[4], fa2[4], fa3[4];
        const u32 tgt = (u32)t;
        u32 fresh = 0;                 // wave-uniform chunk mask (via __all)
        while (fresh != 0xFu) {
            #pragma unroll
            for (int ks = 0; ks < 4; ++ks) {
                if (fresh & (1u << ks)) continue;
                const u64* ap = abase + ks * 32 + quad * 8;
                u64 w[8];
                #pragma unroll
                for (int j = 0; j < 8; ++j) w[j] = ld_agent_u64(ap + j);
                bool ok = true;
                #pragma unroll
                for (int j = 0; j < 8; ++j) ok &= ((u32)(w[j] >> 48) == tgt);
                if (__all((int)ok)) {
                    short8 a1, a2, a3;
                    #pragma unroll
                    for (int j = 0; j < 8; ++j) {
                        const u32 lo = (u32)w[j];
                        const u32 hi = (u32)(w[j] >> 32);
                        a1[j] = (short)(lo & 0xffffu);
                        a2[j] = (short)(lo >> 16);
                        a3[j] = (short)(hi & 0xffffu);
                    }
                    fa1[ks] = a1; fa2[ks] = a2; fa3[ks] = a3;
                    fresh |= 1u << ks;
                }
            }
        }

        // ---- MFMA (same 6-product bf16x3 scheme as before) ----
        f32x4 acc[2][2] = {{{0.f,0.f,0.f,0.f},{0.f,0.f,0.f,0.f}},
                           {{0.f,0.f,0.f,0.f},{0.f,0.f,0.f,0.f}}};
        #pragma unroll
        for (int ks = 0; ks < 4; ++ks) {
            #pragma unroll
            for (int nq = 0; nq < 2; ++nq) {
                acc[nq][0] = __builtin_amdgcn_mfma_f32_16x16x32_bf16(fa1[ks], bfr[ks][nq][0], acc[nq][0], 0, 0, 0);
                acc[nq][1] = __builtin_amdgcn_mfma_f32_16x16x32_bf16(fa2[ks], bfr[ks][nq][0], acc[nq][1], 0, 0, 0);
                acc[nq][0] = __builtin_amdgcn_mfma_f32_16x16x32_bf16(fa1[ks], bfr[ks][nq][1], acc[nq][0], 0, 0, 0);
                acc[nq][1] = __builtin_amdgcn_mfma_f32_16x16x32_bf16(fa2[ks], bfr[ks][nq][1], acc[nq][1], 0, 0, 0);
                acc[nq][0] = __builtin_amdgcn_mfma_f32_16x16x32_bf16(fa1[ks], bfr[ks][nq][2], acc[nq][0], 0, 0, 0);
                acc[nq][1] = __builtin_amdgcn_mfma_f32_16x16x32_bf16(fa3[ks], bfr[ks][nq][0], acc[nq][1], 0, 0, 0);
            }
        }

        // ---- all-wave k-reduction: every wave publishes, every lane owns 1 elem
        red[tb][kq][0][lane] = acc[0][0] + acc[0][1];
        red[tb][kq][1][lane] = acc[1][0] + acc[1][1];
        // single barrier/step: also drains vmcnt(0) -> all waves' state-t loads
        // are complete before any lane stores state t+1 (WAR chain anchor).
        __syncthreads();

        float s = xv;
        #pragma unroll
        for (int k2 = 0; k2 < 8; ++k2)
            s += ((const float*)&red[tb][k2][enq][ele])[eje];
        s = fminf(fmaxf(s, 0.f), CLIPV);

        // producer-side exact bf16x3 trunc split (identical math to old
        // consumer-side split -> bit-identical result), pack with tag t+1
        const u32 xb = __float_as_uint(s);
        const u16 s1 = (u16)(xb >> 16);
        const float r1 = s - bf16_f(s1);
        const u16 s2 = (u16)(__float_as_uint(r1) >> 16);
        const float r2 = r1 - bf16_f(s2);
        const u16 s3 = (u16)(__float_as_uint(r2) >> 16);
        const u64 wv = (u64)s1 | ((u64)s2 << 16) | ((u64)s3 << 32) |
                       ((u64)(u32)(t + 1) << 48);
        st_agent_u64(hbuf + db + hoff, wv);
    }

    // ---- epilogue: out = hf + hb (state 800 lives in buffer 0, tag==800) ----
    if (rg < 2) {
        const int r = tid >> 5, c = tid & 31;
        const int b = R0 + r;
        const u64* pf = hbuf + (size_t)b * UNITS + u0 + c;
        const u64* pb = hbuf + (size_t)(b + 32) * UNITS + u0 + c;
        u64 wf, wb;
        do { wf = ld_agent_u64(pf); } while ((u32)(wf >> 48) != (u32)T_STEPS);
        do { wb = ld_agent_u64(pb); } while ((u32)(wb >> 48) != (u32)T_STEPS);
        const float hf = bf16_f((u16)wf) + bf16_f((u16)(wf >> 16)) + bf16_f((u16)(wf >> 32));
        const float hb = bf16_f((u16)wb) + bf16_f((u16)(wb >> 16)) + bf16_f((u16)(wb >> 32));
        out[(size_t)b * UNITS + u0 + c] = hf + hb;
    }
}

// ---------------------------------------------------------------------------
extern "C" void kernel_launch(void* const* d_in, const int* in_sizes, int n_in,
                              void* d_out, int out_size, void* d_ws, size_t ws_size,
                              hipStream_t stream) {
    const float* inp  = (const float*)d_in[0];   // [32][800][161]
    const float* W    = (const float*)d_in[1];   // [161][1024]
    const float* U    = (const float*)d_in[2];   // [1024][1024]
    const float* bias = (const float*)d_in[3];   // [1024]
    float* out = (float*)d_out;                  // [32][1024]

    u16*   Ut1 = (u16*)d_ws;                              // 3 x 2 MB bf16 planes
    u16*   Ut2 = Ut1 + (size_t)UNITS * UNITS;
    u16*   Ut3 = Ut2 + (size_t)UNITS * UNITS;
    float* xW  = (float*)(Ut3 + (size_t)UNITS * UNITS);   // 104.9 MB
    u64*   hbuf = (u64*)(xW + (size_t)T_STEPS * BATCH * UNITS); // 2 x 512 KB packed

    init_ws<<<64, 256, 0, stream>>>(hbuf);
    u_split_t<<<dim3(32, 32), 256, 0, stream>>>(U, Ut1, Ut2, Ut3);
    xw_gemm<<<dim3(800, 4), 256, 0, stream>>>(inp, W, bias, xW);

    void* args[] = {(void*)&xW, (void*)&Ut1, (void*)&Ut2, (void*)&Ut3,
                    (void*)&hbuf, (void*)&out};
    hipLaunchCooperativeKernel((const void*)rnn_scan, dim3(128), dim3(512),
                               args, 0, stream);
}